// Round 9
// baseline (441.519 us; speedup 1.0000x reference)
//
#include <hip/hip_runtime.h>
#include <hip/hip_bf16.h>

typedef unsigned short u16;
typedef short bf16x8 __attribute__((ext_vector_type(8)));
typedef float f32x4 __attribute__((ext_vector_type(4)));
typedef float f32x2 __attribute__((ext_vector_type(2)));

#define CH_SHIFT 12  // 4096 h8 rows = 2 MiB window per src-chunk

__device__ __forceinline__ u16 f2b(float f) {
    unsigned x = __float_as_uint(f);
    return (u16)((x + 0x7fffu + ((x >> 16) & 1u)) >> 16);
}

// pack two f32 to bf16x2 by truncation: one v_perm_b32
__device__ __forceinline__ int pkbf(float lo, float hi) {
    return __builtin_amdgcn_perm(__float_as_uint(hi), __float_as_uint(lo), 0x07060302);
}

__global__ void cast_wt_kernel(const float* __restrict__ W, u16* __restrict__ Wt) {
    int idx = blockIdx.x * blockDim.x + threadIdx.x;  // 512*512
    int n = idx >> 9, k = idx & 511;
    Wt[idx] = f2b(W[k * 512 + n]);
}

// ---------------- GEMM fused: f32 A staging + h8 (fp8) + attention logits ----------------
__global__ __launch_bounds__(256, 2) void gemm_fused2(
    const float* __restrict__ xA, const float* __restrict__ xW, const u16* __restrict__ Bt,
    unsigned char* __restrict__ h8, const float* __restrict__ att_src,
    const float* __restrict__ att_dst, float* __restrict__ asrc, float* __restrict__ adst,
    int N, int Mpad) {
    __shared__ float lA[128 * 32];
    __shared__ u16 lB[128 * 32];
    __shared__ float sred[2][128][2];
    const int tid = threadIdx.x;
    const int w = tid >> 6, l = tid & 63;
    const int row0 = blockIdx.y * 128;
    const int head = blockIdx.x;
    const int col0 = head * 128;
    const int wr = w >> 1, wc = w & 1;
    const int mlane = l & 15, quad = l >> 4;

    const float* src = (row0 >= Mpad) ? xW : xA;
    const int rbase = row0 - (row0 >= Mpad ? Mpad : 0);
    const int arow = (w << 3) + (l >> 3);
    const int acol = (l & 7) << 2;
    const int srow = (w << 4) + (l >> 2);
    const int scol = (l & 3) << 3;

    f32x4 acc[4][4];
#pragma unroll
    for (int i = 0; i < 4; i++)
#pragma unroll
        for (int j = 0; j < 4; j++) acc[i][j] = f32x4{0.f, 0.f, 0.f, 0.f};

    for (int k0 = 0; k0 < 512; k0 += 32) {
#pragma unroll
        for (int g = 0; g < 4; ++g) {
            int lrow = rbase + g * 32 + arow;
            lrow = min(lrow, N - 1);
            const float* ga = src + (size_t)lrow * 512 + k0 + acol;
            float* la = lA + (g * 32 + (w << 3)) * 32;
            __builtin_amdgcn_global_load_lds((const __attribute__((address_space(1))) void*)ga,
                                             (__attribute__((address_space(3))) void*)la, 16, 0, 0);
        }
#pragma unroll
        for (int s = 0; s < 2; ++s) {
            const u16* gb = Bt + (size_t)(col0 + s * 64 + srow) * 512 + (k0 + scol);
            u16* lb = lB + s * 2048 + w * 512;
            __builtin_amdgcn_global_load_lds((const __attribute__((address_space(1))) void*)gb,
                                             (__attribute__((address_space(3))) void*)lb, 16, 0, 0);
        }
        __syncthreads();
        bf16x8 af[4], bfr[4];
#pragma unroll
        for (int i = 0; i < 4; i++) {
            const float* ap = &lA[(wr * 64 + i * 16 + mlane) * 32 + quad * 8];
            float4 f0 = *(const float4*)ap;
            float4 f1 = *(const float4*)(ap + 4);
            int* ai = (int*)&af[i];
            ai[0] = pkbf(f0.x, f0.y);
            ai[1] = pkbf(f0.z, f0.w);
            ai[2] = pkbf(f1.x, f1.y);
            ai[3] = pkbf(f1.z, f1.w);
            bfr[i] = *(const bf16x8*)&lB[(wc * 64 + i * 16 + mlane) * 32 + quad * 8];
        }
#pragma unroll
        for (int i = 0; i < 4; i++)
#pragma unroll
            for (int j = 0; j < 4; j++)
                acc[i][j] = __builtin_amdgcn_mfma_f32_16x16x32_bf16(af[i], bfr[j], acc[i][j], 0, 0, 0);
        __syncthreads();
    }

    float as_j[4], ad_j[4];
#pragma unroll
    for (int j = 0; j < 4; j++) {
        as_j[j] = att_src[col0 + wc * 64 + j * 16 + mlane];
        ad_j[j] = att_dst[col0 + wc * 64 + j * 16 + mlane];
    }
#pragma unroll
    for (int i = 0; i < 4; i++) {
#pragma unroll
        for (int r = 0; r < 4; r++) {
            float vs = 0.f, vd = 0.f;
#pragma unroll
            for (int j = 0; j < 4; j++) {
                float hv = acc[i][j][r];
                vs += hv * as_j[j];
                vd += hv * ad_j[j];
            }
#pragma unroll
            for (int o = 8; o >= 1; o >>= 1) {
                vs += __shfl_xor(vs, o);
                vd += __shfl_xor(vd, o);
            }
            if (mlane == 0) {
                int lrow = wr * 64 + i * 16 + quad * 4 + r;
                sred[0][lrow][wc] = vs;
                sred[1][lrow][wc] = vd;
            }
        }
    }
#pragma unroll
    for (int i = 0; i < 4; i++)
#pragma unroll
        for (int j = 0; j < 4; j++)
#pragma unroll
            for (int r = 0; r < 4; r++) {
                int rg = row0 + wr * 64 + i * 16 + quad * 4 + r;
                int cg = col0 + wc * 64 + j * 16 + mlane;
                float v = acc[i][j][r];
                unsigned pk = __builtin_amdgcn_cvt_pk_fp8_f32(v, v, 0, false);
                h8[(size_t)rg * 512 + cg] = (unsigned char)(pk & 0xff);
            }
    __syncthreads();
    {
        int row = tid & 127, which = tid >> 7;
        int rg = row0 + row;  // hrow
        float v = sred[which][row][0] + sred[which][row][1];
        (which ? adst : asrc)[(rg << 2) + head] = v;
    }
}

// ---------------- 2-level CSR over hrow space: seg = dst_hrow*NC + (src_hrow>>CH_SHIFT) ----------------
__global__ void csr_count2(const int* __restrict__ adj, const int* __restrict__ wadj,
                           int E, int Mpad, int NC, int* __restrict__ deg2) {
    int i = blockIdx.x * blockDim.x + threadIdx.x;
    if (i < 2 * E) {
        int s, d;
        if (i < E) {
            s = adj[i];
            d = adj[E + i];
        } else {
            s = wadj[i - E] + Mpad;
            d = wadj[E + (i - E)] + Mpad;
        }
        atomicAdd(&deg2[d * NC + (s >> CH_SHIFT)], 1);
    }
}

// scanA over segments; self-loop (+1) folded in for valid rows' own chunk
__global__ __launch_bounds__(256) void scanA2(const int* __restrict__ deg2, int* __restrict__ off2,
                                              int* __restrict__ bsum, int nseg, int N, int Mpad,
                                              int NC) {
    __shared__ int wsum[4];
    int tid = threadIdx.x, lane = tid & 63, wid = tid >> 6;
    int j = blockIdx.x * 256 + tid;
    int d = 0;
    if (j < nseg) {
        d = deg2[j];
        int node = j / NC;
        int k = j - node * NC;
        int valid = (node < N) || (node >= Mpad && node < Mpad + N);
        if (valid && ((node >> CH_SHIFT) == k)) d += 1;
    }
    int x = d;
#pragma unroll
    for (int o = 1; o < 64; o <<= 1) {
        int y = __shfl_up(x, (unsigned)o, 64);
        if (lane >= o) x += y;
    }
    if (lane == 63) wsum[wid] = x;
    __syncthreads();
    int woff = 0;
    for (int jj = 0; jj < wid; ++jj) woff += wsum[jj];
    if (j < nseg) off2[j] = woff + x - d;
    if (tid == 255) bsum[blockIdx.x] = woff + x;
}

// single-block looped scan over block sums
__global__ __launch_bounds__(256) void scanB_loop(const int* __restrict__ bsum,
                                                  int* __restrict__ bbase, int nb,
                                                  int* __restrict__ off2, int nseg) {
    __shared__ int wsum[4];
    __shared__ int s_run;
    int tid = threadIdx.x, lane = tid & 63, wid = tid >> 6;
    if (tid == 0) s_run = 0;
    __syncthreads();
    int nloop = (nb + 255) / 256;
    for (int c2 = 0; c2 < nloop; ++c2) {
        int i = c2 * 256 + tid;
        int d = (i < nb) ? bsum[i] : 0;
        int x = d;
#pragma unroll
        for (int o = 1; o < 64; o <<= 1) {
            int y = __shfl_up(x, (unsigned)o, 64);
            if (lane >= o) x += y;
        }
        if (lane == 63) wsum[wid] = x;
        __syncthreads();
        int woff = 0;
        for (int jj = 0; jj < wid; ++jj) woff += wsum[jj];
        int run = s_run;
        if (i < nb) bbase[i] = run + woff + x - d;
        int total = wsum[0] + wsum[1] + wsum[2] + wsum[3];
        __syncthreads();
        if (tid == 0) s_run = run + total;
        __syncthreads();
    }
    if (tid == 0) off2[nseg] = s_run;
}

// finalize offsets; insert self-loop at start of (dst, chunk(dst)) segment
__global__ void scanC2(int* __restrict__ off2, const int* __restrict__ bbase,
                       int* __restrict__ cursor2, int* __restrict__ csrc,
                       int nseg, int N, int Mpad, int NC) {
    int j = blockIdx.x * blockDim.x + threadIdx.x;
    if (j >= nseg) return;
    int o = off2[j] + bbase[j >> 8];
    off2[j] = o;
    int node = j / NC;
    int k = j - node * NC;
    int valid = (node < N) || (node >= Mpad && node < Mpad + N);
    int self = (valid && ((node >> CH_SHIFT) == k)) ? 1 : 0;
    if (self) csrc[o] = node;
    cursor2[j] = o + self;
}

__global__ void csr_scatter2(const int* __restrict__ adj, const int* __restrict__ wadj,
                             int E, int Mpad, int NC,
                             int* __restrict__ cursor2, int* __restrict__ csrc) {
    int i = blockIdx.x * blockDim.x + threadIdx.x;
    if (i < 2 * E) {
        int s, d;
        if (i < E) {
            s = adj[i];
            d = adj[E + i];
        } else {
            s = wadj[i - E] + Mpad;
            d = wadj[E + (i - E)] + Mpad;
        }
        int p = atomicAdd(&cursor2[d * NC + (s >> CH_SHIFT)], 1);
        csrc[p] = s;
    }
}

// ---------------- chunk-major fused softmax + gather ----------------
// Wave owns 4 dsts (acc resident in regs); outer loop sweeps src-chunks so the
// whole device gathers from a ~2MB window at a time (XCD-L2 resident).
__device__ __forceinline__ void edge2(int hr, float ad, int head, const float* __restrict__ asrc,
                                      const unsigned char* __restrict__ h8, int c,
                                      float* acc, float& dsum) {
    float e = asrc[(hr << 2) + head] + ad;
    e = fmaxf(e, 0.2f * e);
    float ex = __expf(e);
    dsum += ex;
    int2 hv = *(const int2*)(h8 + (((size_t)hr) << 9) + c);
    f32x2 f01 = __builtin_amdgcn_cvt_pk_f32_fp8(hv.x, false);
    f32x2 f23 = __builtin_amdgcn_cvt_pk_f32_fp8(hv.x, true);
    f32x2 f45 = __builtin_amdgcn_cvt_pk_f32_fp8(hv.y, false);
    f32x2 f67 = __builtin_amdgcn_cvt_pk_f32_fp8(hv.y, true);
    acc[0] += ex * f01.x; acc[1] += ex * f01.y;
    acc[2] += ex * f23.x; acc[3] += ex * f23.y;
    acc[4] += ex * f45.x; acc[5] += ex * f45.y;
    acc[6] += ex * f67.x; acc[7] += ex * f67.y;
}

__global__ __launch_bounds__(256) void gat_aggregate7(
    const unsigned char* __restrict__ h8, const float* __restrict__ asrc,
    const float* __restrict__ adst, const int* __restrict__ off2, const int* __restrict__ csrc,
    const float* __restrict__ bias, float* __restrict__ partAB, int Mpad, int NC) {
    __shared__ float spool[1024];
    int tid = threadIdx.x;
    for (int i = tid; i < 1024; i += 256) spool[i] = 0.f;
    __syncthreads();
    int w = tid >> 6, l = tid & 63;
    int c = l << 3, head = l >> 4;
    int d0 = (blockIdx.x * 4 + w) * 4;  // 4 consecutive dsts per wave, exact cover
    float ad[4];
    float dsum[4] = {0.f, 0.f, 0.f, 0.f};
    float acc[4][8] = {};
#pragma unroll
    for (int k = 0; k < 4; ++k) ad[k] = adst[((d0 + k) << 2) + head];
    const int segbase = d0 * NC;
    for (int cc = 0; cc < NC; ++cc) {
#pragma unroll
        for (int k = 0; k < 4; ++k) {
            int j = segbase + k * NC + cc;
            int p0 = off2[j], p1 = off2[j + 1];
            int p = p0;
            for (; p + 2 <= p1; p += 2) {
                int2 ca = *(const int2*)(csrc + p);
                edge2(ca.x, ad[k], head, asrc, h8, c, acc[k], dsum[k]);
                edge2(ca.y, ad[k], head, asrc, h8, c, acc[k], dsum[k]);
            }
            if (p < p1) edge2(csrc[p], ad[k], head, asrc, h8, c, acc[k], dsum[k]);
        }
    }
    float bb[8];
#pragma unroll
    for (int k2 = 0; k2 < 8; ++k2) bb[k2] = bias[c + k2];
#pragma unroll
    for (int k = 0; k < 4; ++k) {
        if (dsum[k] > 0.f) {  // pad rows have no edges at all
            float inv = 1.f / dsum[k];
            int base = (d0 + k < Mpad) ? 0 : 512;
#pragma unroll
            for (int k2 = 0; k2 < 8; ++k2) {
                float o = acc[k][k2] * inv + bb[k2];
                atomicAdd(&spool[base + c + k2], fmaxf(o, 0.01f * o));
            }
        }
    }
    __syncthreads();
    int base = (blockIdx.x & 63) << 9;
    for (int i = tid; i < 1024; i += 256) {
        float* dp = (i < 512) ? (partAB + base + i) : (partAB + 64 * 512 + base + (i - 512));
        atomicAdd(dp, spool[i]);
    }
}

// ---------------- fused mean-pool reduce + fc + concat ----------------
__global__ __launch_bounds__(256) void fc_final2(
    const float* __restrict__ partAB, const float* __restrict__ w, const float* __restrict__ b,
    float* __restrict__ out, float invN) {
    __shared__ float gA[512], gB[512];
    __shared__ float rA[256], rB[256];
    int t = threadIdx.x;
    for (int i = t; i < 512; i += 256) {
        float sA = 0.f, sB = 0.f;
        for (int r = 0; r < 64; ++r) {
            sA += partAB[r * 512 + i];
            sB += partAB[64 * 512 + r * 512 + i];
        }
        gA[i] = sA * invN;
        gB[i] = sB * invN;
    }
    __syncthreads();
    int jj = t & 31, ks = t >> 5;
    int j = blockIdx.x * 32 + jj;
    float sA = 0.f, sB = 0.f;
    for (int k = ks * 64; k < ks * 64 + 64; ++k) {
        float wv = w[k * 512 + j];
        sA += gA[k] * wv;
        sB += gB[k] * wv;
    }
    rA[t] = sA;
    rB[t] = sB;
    __syncthreads();
    if (ks == 0) {
#pragma unroll
        for (int s2 = 1; s2 < 8; ++s2) {
            sA += rA[jj + 32 * s2];
            sB += rB[jj + 32 * s2];
        }
        sA += b[j];
        sB += b[j];
        sA = sA >= 0.f ? sA : 0.01f * sA;
        sB = sB >= 0.f ? sB : 0.01f * sB;
        out[j] = sA;
        out[512 + j] = sB;
        out[1024 + j] = sA - sB;
    }
}

// ---------------- launch ----------------
extern "C" void kernel_launch(void* const* d_in, const int* in_sizes, int n_in,
                              void* d_out, int out_size, void* d_ws, size_t ws_size,
                              hipStream_t stream) {
    const float* x = (const float*)d_in[0];
    const int* adj = (const int*)d_in[1];
    const float* wtx = (const float*)d_in[2];
    const int* wadj = (const int*)d_in[3];
    const float* W = (const float*)d_in[4];
    const float* att_s = (const float*)d_in[5];
    const float* att_d = (const float*)d_in[6];
    const float* bias = (const float*)d_in[7];
    const float* fc1w = (const float*)d_in[8];
    const float* fc1b = (const float*)d_in[9];
    float* out = (float*)d_out;

    const int N = in_sizes[0] / 512;  // 20000
    const int E = in_sizes[1] / 2;    // 320000
    const int Mpad = ((N + 127) / 128) * 128;
    const int R2 = 2 * Mpad;                                  // hrow space
    const int NC = (R2 + (1 << CH_SHIFT) - 1) >> CH_SHIFT;    // src chunks (10)
    const int nseg = R2 * NC;
    const int nbA = (nseg + 255) / 256;

    char* p = (char*)d_ws;
    auto alloc = [&](size_t bytes) -> char* {
        char* r = p;
        p += (bytes + 255) & ~(size_t)255;
        return r;
    };
    unsigned char* h8 = (unsigned char*)alloc((size_t)R2 * 512);
    u16* Wt = (u16*)alloc(512 * 512 * 2);
    float* asrc = (float*)alloc((size_t)R2 * 4 * 4);
    float* adst = (float*)alloc((size_t)R2 * 4 * 4);
    int* deg2 = (int*)alloc((size_t)nseg * 4);
    int* off2 = (int*)alloc((size_t)(nseg + 1) * 4);
    int* cursor2 = (int*)alloc((size_t)nseg * 4);
    int* bsum = (int*)alloc((size_t)(nbA + 1) * 4);
    int* bbase = (int*)alloc((size_t)(nbA + 1) * 4);
    int* csrc = (int*)alloc((size_t)2 * (E + N) * 4);
    float* partAB = (float*)alloc((size_t)2 * 64 * 512 * 4);

    hipMemsetAsync(partAB, 0, (size_t)2 * 64 * 512 * 4, stream);
    hipMemsetAsync(deg2, 0, (size_t)nseg * 4, stream);
    cast_wt_kernel<<<(512 * 512) / 256, 256, 0, stream>>>(W, Wt);

    // 2-level CSR build (independent of GEMM)
    csr_count2<<<(2 * E + 255) / 256, 256, 0, stream>>>(adj, wadj, E, Mpad, NC, deg2);
    scanA2<<<nbA, 256, 0, stream>>>(deg2, off2, bsum, nseg, N, Mpad, NC);
    scanB_loop<<<1, 256, 0, stream>>>(bsum, bbase, nbA, off2, nseg);
    scanC2<<<nbA, 256, 0, stream>>>(off2, bbase, cursor2, csrc, nseg, N, Mpad, NC);
    csr_scatter2<<<(2 * E + 255) / 256, 256, 0, stream>>>(adj, wadj, E, Mpad, NC, cursor2, csrc);

    // fused GEMM from f32 inputs (head fastest -> A-stripe reuse)
    dim3 gg(4, R2 / 128, 1);
    gemm_fused2<<<gg, 256, 0, stream>>>(x, wtx, Wt, h8, att_s, att_d, asrc, adst, N, Mpad);

    // chunk-major aggregate: R2/16 blocks, each wave owns 4 dsts
    gat_aggregate7<<<R2 / 16, 256, 0, stream>>>(h8, asrc, adst, off2, csrc, bias, partAB,
                                                Mpad, NC);

    fc_final2<<<16, 256, 0, stream>>>(partAB, fc1w, fc1b, out, 1.0f / (float)N);
}